// Round 1
// baseline (285.249 us; speedup 1.0000x reference)
//
#include <hip/hip_runtime.h>
#include <cmath>

#define BATCH 4
#define CDIM  64
#define CK    8
#define NSEQ  4096
#define NT    64   // n-tile size in attention kernel
#define MT    32   // m columns per block

// -------------------------------------------------------------------------
// Kernel 1: compute f = wq@x, g = wk@x, h = wv@x
// Layouts (float): f[B][CK][N], g[B][CK][N], h[B][CDIM][N] in workspace.
// Grid: 256 blocks x 256 threads. Block handles 64 consecutive n of one b.
// Thread layout: 64 n x 4 c-quarters; partial sums reduced via shfl_xor.
// -------------------------------------------------------------------------
__global__ __launch_bounds__(256) void fgh_kernel(
    const float* __restrict__ x,  const float* __restrict__ wq,
    const float* __restrict__ wk, const float* __restrict__ wv,
    float* __restrict__ fbuf, float* __restrict__ gbuf, float* __restrict__ hbuf)
{
    __shared__ __align__(16) float s_wq[CDIM][CK];   // s_wq[c][k] = wq[k][c]
    __shared__ __align__(16) float s_wk[CDIM][CK];
    __shared__ __align__(16) float s_wv[CDIM][68];   // s_wv[c][d] = wv[d][c], padded row

    const int t = threadIdx.x;
    #pragma unroll
    for (int u = 0; u < 2; ++u) {
        const int i = t + u * 256;        // 512 = 8k x 64c
        const int k = i >> 6, c = i & 63;
        s_wq[c][k] = wq[i];
        s_wk[c][k] = wk[i];
    }
    #pragma unroll
    for (int u = 0; u < 16; ++u) {
        const int i = t + u * 256;        // 4096 = 64d x 64c
        const int d = i >> 6, c = i & 63;
        s_wv[c][d] = wv[i];
    }
    __syncthreads();

    const int b  = blockIdx.x >> 6;           // 4 batches x 64 chunks
    const int n0 = (blockIdx.x & 63) * 64;
    const int nl = t >> 2;                    // 0..63
    const int q  = t & 3;                     // c-quarter
    const int n  = n0 + nl;

    float fa[CK]   = {0.f};
    float ga[CK]   = {0.f};
    float ha[CDIM] = {0.f};

    #pragma unroll
    for (int ci = 0; ci < 16; ++ci) {
        const int c   = q * 16 + ci;
        const float xv = x[(b * CDIM + c) * NSEQ + n];

        const float4 q0 = *(const float4*)&s_wq[c][0];
        const float4 q1 = *(const float4*)&s_wq[c][4];
        fa[0] += q0.x * xv; fa[1] += q0.y * xv; fa[2] += q0.z * xv; fa[3] += q0.w * xv;
        fa[4] += q1.x * xv; fa[5] += q1.y * xv; fa[6] += q1.z * xv; fa[7] += q1.w * xv;

        const float4 k0 = *(const float4*)&s_wk[c][0];
        const float4 k1v = *(const float4*)&s_wk[c][4];
        ga[0] += k0.x * xv; ga[1] += k0.y * xv; ga[2] += k0.z * xv; ga[3] += k0.w * xv;
        ga[4] += k1v.x * xv; ga[5] += k1v.y * xv; ga[6] += k1v.z * xv; ga[7] += k1v.w * xv;

        #pragma unroll
        for (int u = 0; u < 16; ++u) {
            const float4 v = *(const float4*)&s_wv[c][u * 4];
            ha[u*4+0] += v.x * xv; ha[u*4+1] += v.y * xv;
            ha[u*4+2] += v.z * xv; ha[u*4+3] += v.w * xv;
        }
    }

    // reduce partial sums across the 4-lane c-quarter group
    #pragma unroll
    for (int k = 0; k < CK; ++k) {
        fa[k] += __shfl_xor(fa[k], 1); fa[k] += __shfl_xor(fa[k], 2);
        ga[k] += __shfl_xor(ga[k], 1); ga[k] += __shfl_xor(ga[k], 2);
    }
    #pragma unroll
    for (int d = 0; d < CDIM; ++d) {
        ha[d] += __shfl_xor(ha[d], 1); ha[d] += __shfl_xor(ha[d], 2);
    }

    // writes: split outputs across the 4 lanes of the group
    #pragma unroll
    for (int k = 0; k < CK; ++k) {
        if ((k >> 1) == q) {
            fbuf[(b * CK + k) * NSEQ + n] = fa[k];
            gbuf[(b * CK + k) * NSEQ + n] = ga[k];
        }
    }
    #pragma unroll
    for (int d = 0; d < CDIM; ++d) {
        if ((d >> 4) == q) hbuf[(b * CDIM + d) * NSEQ + n] = ha[d];
    }
}

// -------------------------------------------------------------------------
// Kernel 2: flash-style attention over n for each output column m.
//   scores[n,m] = sum_k f[k,n] * g[k,m];  beta = softmax over n
//   o[c,m] = sum_n h[c,n] * beta[n,m];  out = gamma*o/L + x
// Grid: B * (N/MT) = 512 blocks x 256 threads.
// Thread: m_l = t>>3 (one m column), r = t&7 (n-subset: n = r + 8j).
// Per-thread o[64] accumulator; final merge via 8-lane shfl butterfly.
// -------------------------------------------------------------------------
__global__ __launch_bounds__(256) void attn_kernel(
    const float* __restrict__ x,    const float* __restrict__ fbuf,
    const float* __restrict__ gbuf, const float* __restrict__ hbuf,
    const float* __restrict__ gamma, float* __restrict__ out)
{
    __shared__ __align__(16) float s_f[CK * NT];   // [k][n] flat, 512 floats
    __shared__ __align__(16) float s_h[NT * 68];   // [n][c] rows padded to 68

    const int t   = threadIdx.x;
    const int b   = blockIdx.x >> 7;     // 128 m-tiles per batch
    const int mt  = blockIdx.x & 127;
    const int m_l = t >> 3;              // 0..31
    const int r   = t & 7;               // n-split index
    const int m   = mt * MT + m_l;

    const float gscale = gamma[0];

    float g_reg[CK];
    #pragma unroll
    for (int k = 0; k < CK; ++k) g_reg[k] = gbuf[(b * CK + k) * NSEQ + m];

    float o[CDIM] = {0.f};
    float mrun = -1e30f, lrun = 0.f;

    for (int nt = 0; nt < NSEQ / NT; ++nt) {
        const int n0 = nt * NT;
        __syncthreads();   // protect LDS from previous-iteration readers

        // stage f tile: flat copy (global [k][n-run] -> LDS [k][n])
        #pragma unroll
        for (int u = 0; u < 2; ++u) {
            const int i = t + u * 256;
            const int k = i >> 6, j = i & 63;
            s_f[i] = fbuf[(b * CK + k) * NSEQ + n0 + j];
        }
        // stage h tile transposed: hbuf[b][c][n] -> s_h[n][c]
        #pragma unroll
        for (int u = 0; u < 4; ++u) {
            const int ch = t + u * 256;          // 1024 float4 chunks
            const int c  = ch >> 4;
            const int nn = (ch & 15) * 4;
            const float4 hv = *(const float4*)&hbuf[(b * CDIM + c) * NSEQ + n0 + nn];
            s_h[(nn + 0) * 68 + c] = hv.x;
            s_h[(nn + 1) * 68 + c] = hv.y;
            s_h[(nn + 2) * 68 + c] = hv.z;
            s_h[(nn + 3) * 68 + c] = hv.w;
        }
        __syncthreads();

        // scores for my 8 n's (n = r + 8j)
        float sc[8];
        #pragma unroll
        for (int j = 0; j < 8; ++j) {
            const int nl = r + 8 * j;
            float s = 0.f;
            #pragma unroll
            for (int k = 0; k < CK; ++k) s += s_f[k * 64 + nl] * g_reg[k];
            sc[j] = s;
        }
        float tmax = sc[0];
        #pragma unroll
        for (int j = 1; j < 8; ++j) tmax = fmaxf(tmax, sc[j]);

        if (tmax > mrun) {
            const float scale = __expf(mrun - tmax);
            lrun *= scale;
            #pragma unroll
            for (int c = 0; c < CDIM; ++c) o[c] *= scale;
            mrun = tmax;
        }

        float p[8];
        #pragma unroll
        for (int j = 0; j < 8; ++j) { p[j] = __expf(sc[j] - mrun); lrun += p[j]; }

        // o[c] += p_j * h[c, n]   (s_h reads: 8 distinct rows, disjoint bank spans)
        #pragma unroll
        for (int j = 0; j < 8; ++j) {
            const float pj  = p[j];
            const int base  = (r + 8 * j) * 68;
            #pragma unroll
            for (int c4 = 0; c4 < 16; ++c4) {
                const float4 hv = *(const float4*)&s_h[base + c4 * 4];
                o[c4*4+0] += pj * hv.x; o[c4*4+1] += pj * hv.y;
                o[c4*4+2] += pj * hv.z; o[c4*4+3] += pj * hv.w;
            }
        }
    }

    // merge the 8 partial (m, l, o) states of this m-group (lanes m_l*8 .. +7)
    float gm = mrun;
    #pragma unroll
    for (int d = 1; d < 8; d <<= 1) gm = fmaxf(gm, __shfl_xor(gm, d));
    const float msc = __expf(mrun - gm);
    lrun *= msc;
    #pragma unroll
    for (int c = 0; c < CDIM; ++c) o[c] *= msc;
    #pragma unroll
    for (int d = 1; d < 8; d <<= 1) lrun += __shfl_xor(lrun, d);
    #pragma unroll
    for (int c = 0; c < CDIM; ++c) {
        #pragma unroll
        for (int d = 1; d < 8; d <<= 1) o[c] += __shfl_xor(o[c], d);
    }
    const float inv = 1.f / lrun;

    // out[b][c][m] = gamma * o[c]/L + x[b][c][m]; lane r writes c = r*8..r*8+7
    #pragma unroll
    for (int c = 0; c < CDIM; ++c) {
        if ((c >> 3) == r) {
            const int idx = (b * CDIM + c) * NSEQ + m;
            out[idx] = gscale * o[c] * inv + x[idx];
        }
    }
}

extern "C" void kernel_launch(void* const* d_in, const int* in_sizes, int n_in,
                              void* d_out, int out_size, void* d_ws, size_t ws_size,
                              hipStream_t stream) {
    const float* x     = (const float*)d_in[0];
    const float* wq    = (const float*)d_in[1];
    const float* wk    = (const float*)d_in[2];
    const float* wv    = (const float*)d_in[3];
    const float* gamma = (const float*)d_in[4];
    float* out = (float*)d_out;

    float* ws   = (float*)d_ws;
    float* fbuf = ws;                               // B*CK*N   = 131072 floats
    float* gbuf = ws + BATCH * CK * NSEQ;           // B*CK*N   = 131072 floats
    float* hbuf = ws + 2 * BATCH * CK * NSEQ;       // B*CDIM*N = 1048576 floats

    hipLaunchKernelGGL(fgh_kernel, dim3(256), dim3(256), 0, stream,
                       x, wq, wk, wv, fbuf, gbuf, hbuf);
    hipLaunchKernelGGL(attn_kernel, dim3(BATCH * (NSEQ / MT)), dim3(256), 0, stream,
                       x, fbuf, gbuf, hbuf, gamma, out);
}

// Round 2
// 100.893 us; speedup vs baseline: 2.8272x; 2.8272x over previous
//
#include <hip/hip_runtime.h>
#include <hip/hip_bf16.h>
#include <cmath>

#define BATCH  4
#define CDIM   64
#define CK     8
#define NSEQ   4096
#define NSPLIT 4
#define MT     128           // m per block: 4 waves x 32
#define NT     64            // n per tile-iter
#define ITERS  (NSEQ / NSPLIT / NT)   // 16

typedef __attribute__((ext_vector_type(8)))  short short8;
typedef __attribute__((ext_vector_type(16))) float f32x16;

__device__ inline unsigned short f2bf(float f) {
    union { float f; unsigned u; } v; v.f = f;
    unsigned r = v.u + 0x7fff + ((v.u >> 16) & 1);   // round-to-nearest-even
    return (unsigned short)(r >> 16);
}

// -------------------------------------------------------------------------
// Kernel 1 (unchanged from round 1): f = wq@x, g = wk@x, h = wv@x, all fp32.
// f[B][CK][N], g[B][CK][N], h[B][CDIM][N].
// -------------------------------------------------------------------------
__global__ __launch_bounds__(256) void fgh_kernel(
    const float* __restrict__ x,  const float* __restrict__ wq,
    const float* __restrict__ wk, const float* __restrict__ wv,
    float* __restrict__ fbuf, float* __restrict__ gbuf, float* __restrict__ hbuf)
{
    __shared__ __align__(16) float s_wq[CDIM][CK];
    __shared__ __align__(16) float s_wk[CDIM][CK];
    __shared__ __align__(16) float s_wv[CDIM][68];

    const int t = threadIdx.x;
    #pragma unroll
    for (int u = 0; u < 2; ++u) {
        const int i = t + u * 256;
        const int k = i >> 6, c = i & 63;
        s_wq[c][k] = wq[i];
        s_wk[c][k] = wk[i];
    }
    #pragma unroll
    for (int u = 0; u < 16; ++u) {
        const int i = t + u * 256;
        const int d = i >> 6, c = i & 63;
        s_wv[c][d] = wv[i];
    }
    __syncthreads();

    const int b  = blockIdx.x >> 6;
    const int n0 = (blockIdx.x & 63) * 64;
    const int nl = t >> 2;
    const int q  = t & 3;
    const int n  = n0 + nl;

    float fa[CK]   = {0.f};
    float ga[CK]   = {0.f};
    float ha[CDIM] = {0.f};

    #pragma unroll
    for (int ci = 0; ci < 16; ++ci) {
        const int c   = q * 16 + ci;
        const float xv = x[(b * CDIM + c) * NSEQ + n];

        const float4 q0 = *(const float4*)&s_wq[c][0];
        const float4 q1 = *(const float4*)&s_wq[c][4];
        fa[0] += q0.x * xv; fa[1] += q0.y * xv; fa[2] += q0.z * xv; fa[3] += q0.w * xv;
        fa[4] += q1.x * xv; fa[5] += q1.y * xv; fa[6] += q1.z * xv; fa[7] += q1.w * xv;

        const float4 k0  = *(const float4*)&s_wk[c][0];
        const float4 k1v = *(const float4*)&s_wk[c][4];
        ga[0] += k0.x * xv; ga[1] += k0.y * xv; ga[2] += k0.z * xv; ga[3] += k0.w * xv;
        ga[4] += k1v.x * xv; ga[5] += k1v.y * xv; ga[6] += k1v.z * xv; ga[7] += k1v.w * xv;

        #pragma unroll
        for (int u = 0; u < 16; ++u) {
            const float4 v = *(const float4*)&s_wv[c][u * 4];
            ha[u*4+0] += v.x * xv; ha[u*4+1] += v.y * xv;
            ha[u*4+2] += v.z * xv; ha[u*4+3] += v.w * xv;
        }
    }

    #pragma unroll
    for (int k = 0; k < CK; ++k) {
        fa[k] += __shfl_xor(fa[k], 1); fa[k] += __shfl_xor(fa[k], 2);
        ga[k] += __shfl_xor(ga[k], 1); ga[k] += __shfl_xor(ga[k], 2);
    }
    #pragma unroll
    for (int d = 0; d < CDIM; ++d) {
        ha[d] += __shfl_xor(ha[d], 1); ha[d] += __shfl_xor(ha[d], 2);
    }

    #pragma unroll
    for (int k = 0; k < CK; ++k) {
        if ((k >> 1) == q) {
            fbuf[(b * CK + k) * NSEQ + n] = fa[k];
            gbuf[(b * CK + k) * NSEQ + n] = ga[k];
        }
    }
    #pragma unroll
    for (int d = 0; d < CDIM; ++d) {
        if ((d >> 4) == q) hbuf[(b * CDIM + d) * NSEQ + n] = ha[d];
    }
}

// -------------------------------------------------------------------------
// Kernel 2: MFMA flash attention, no-max softmax, n-split x4 with atomics.
// Block: 256 threads (4 waves). Wave w owns m = mt*128 + w*32 + (lane&31),
// full 64 c (2x mfma_f32_32x32x16_bf16 accs). Each lane computes its own
// B-fragment scores p[n] = exp(sum_k f[k,n]*g[k,m]) in fp32 (no LDS for P).
// h staged per 64-n tile as bf16 in LDS, 136B row stride (b64 frag reads).
// -------------------------------------------------------------------------
__global__ __launch_bounds__(256) void attn_kernel(
    const float* __restrict__ fbuf, const float* __restrict__ gbuf,
    const float* __restrict__ hbuf, float* __restrict__ o_acc,
    float* __restrict__ l_acc)
{
    __shared__ __align__(16) float          s_f[CK * NT];     // [k][64] fp32
    __shared__ __align__(16) unsigned short s_h[CDIM * 68];   // [c][68] bf16

    const int t    = threadIdx.x;
    const int lane = t & 63;
    const int w    = t >> 6;
    const int hh   = lane >> 5;       // k-half within wave
    const int lm   = lane & 31;

    const int bid = blockIdx.x;       // 512 = B(4) * mt(32) * s(4)
    const int s   = bid & (NSPLIT - 1);
    const int mt  = (bid >> 2) & 31;
    const int b   = bid >> 7;

    const int m = mt * MT + w * 32 + lm;

    float g_reg[CK];
    #pragma unroll
    for (int k = 0; k < CK; ++k) g_reg[k] = gbuf[(b * CK + k) * NSEQ + m];

    f32x16 acc0 = {};
    f32x16 acc1 = {};
    float lsum = 0.f;

    const float* fb = fbuf + b * CK * NSEQ;
    const float* hb = hbuf + b * CDIM * NSEQ;

    for (int it = 0; it < ITERS; ++it) {
        const int n0 = s * (NSEQ / NSPLIT) + it * NT;
        __syncthreads();
        // stage f tile: [k][64] fp32, 2 floats per thread
        {
            const int i  = t * 2;
            const int k  = i >> 6;
            const int nn = i & 63;
            const float2 fv = *(const float2*)&fb[k * NSEQ + n0 + nn];
            *(float2*)&s_f[k * NT + nn] = fv;
        }
        // stage h tile: fp32 global -> bf16 LDS [c][68]
        {
            const int c  = t >> 2;
            const int ng = t & 3;
            const float* src = &hb[c * NSEQ + n0 + ng * 16];
            #pragma unroll
            for (int q = 0; q < 4; ++q) {
                const float4 hv = *(const float4*)&src[q * 4];
                ushort4 pk;
                pk.x = f2bf(hv.x); pk.y = f2bf(hv.y);
                pk.z = f2bf(hv.z); pk.w = f2bf(hv.w);
                *(ushort4*)&s_h[c * 68 + ng * 16 + q * 4] = pk;
            }
        }
        __syncthreads();

        #pragma unroll
        for (int kc = 0; kc < 4; ++kc) {
            // scores for n = n0 + kc*16 + hh*8 + j  (exactly this lane's B-frag)
            float p[8] = {0.f,0.f,0.f,0.f,0.f,0.f,0.f,0.f};
            const int fo = kc * 16 + hh * 8;
            #pragma unroll
            for (int k = 0; k < CK; ++k) {
                const float4 fa = *(const float4*)&s_f[k * NT + fo];
                const float4 fc = *(const float4*)&s_f[k * NT + fo + 4];
                const float gk = g_reg[k];
                p[0] += fa.x * gk; p[1] += fa.y * gk; p[2] += fa.z * gk; p[3] += fa.w * gk;
                p[4] += fc.x * gk; p[5] += fc.y * gk; p[6] += fc.z * gk; p[7] += fc.w * gk;
            }
            union { short8 v; unsigned short us[8]; } B;
            #pragma unroll
            for (int j = 0; j < 8; ++j) {
                const float e = __expf(p[j]);
                lsum += e;
                B.us[j] = f2bf(e);
            }

            // A-frags: h rows ct*32 + lm, bf16 offset kc*16 + hh*8 (2x b64 each)
            const int ho = kc * 16 + hh * 8;
            union { short8 v; uint2 q2[2]; } A0, A1;
            A0.q2[0] = *(const uint2*)&s_h[lm * 68 + ho];
            A0.q2[1] = *(const uint2*)&s_h[lm * 68 + ho + 4];
            A1.q2[0] = *(const uint2*)&s_h[(32 + lm) * 68 + ho];
            A1.q2[1] = *(const uint2*)&s_h[(32 + lm) * 68 + ho + 4];

            acc0 = __builtin_amdgcn_mfma_f32_32x32x16_bf16(A0.v, B.v, acc0, 0, 0, 0);
            acc1 = __builtin_amdgcn_mfma_f32_32x32x16_bf16(A1.v, B.v, acc1, 0, 0, 0);
        }
    }

    // merge lane pairs (l, l+32) for l, then atomically accumulate partials
    const float ltot = lsum + __shfl_xor(lsum, 32);
    if (hh == 0) atomicAdd(&l_acc[b * NSEQ + m], ltot);

    #pragma unroll
    for (int r = 0; r < 16; ++r) {
        const int c0 = (r & 3) + 8 * (r >> 2) + 4 * hh;   // C/D row mapping
        atomicAdd(&o_acc[(b * CDIM + c0)      * NSEQ + m], acc0[r]);
        atomicAdd(&o_acc[(b * CDIM + 32 + c0) * NSEQ + m], acc1[r]);
    }
}

// -------------------------------------------------------------------------
// Kernel 3: out = gamma * o/l + x
// -------------------------------------------------------------------------
__global__ __launch_bounds__(256) void final_kernel(
    const float* __restrict__ x, const float* __restrict__ o_acc,
    const float* __restrict__ l_acc, const float* __restrict__ gamma,
    float* __restrict__ out)
{
    const int i = blockIdx.x * 256 + threadIdx.x;
    const int m = i & (NSEQ - 1);
    const int b = i >> 18;                       // 64*4096 elems per batch
    out[i] = gamma[0] * o_acc[i] / l_acc[b * NSEQ + m] + x[i];
}

extern "C" void kernel_launch(void* const* d_in, const int* in_sizes, int n_in,
                              void* d_out, int out_size, void* d_ws, size_t ws_size,
                              hipStream_t stream) {
    const float* x     = (const float*)d_in[0];
    const float* wq    = (const float*)d_in[1];
    const float* wk    = (const float*)d_in[2];
    const float* wv    = (const float*)d_in[3];
    const float* gamma = (const float*)d_in[4];
    float* out = (float*)d_out;

    float* ws    = (float*)d_ws;
    float* fbuf  = ws;                                   // 131072 floats
    float* gbuf  = fbuf + BATCH * CK * NSEQ;             // 131072
    float* hbuf  = gbuf + BATCH * CK * NSEQ;             // 1048576
    float* o_acc = hbuf + BATCH * CDIM * NSEQ;           // 1048576
    float* l_acc = o_acc + BATCH * CDIM * NSEQ;          // 16384
    // total ws use: ~9.5 MB

    // zero the atomic accumulators (o_acc and l_acc are contiguous)
    hipMemsetAsync(o_acc, 0,
                   (size_t)(BATCH * CDIM * NSEQ + BATCH * NSEQ) * sizeof(float),
                   stream);

    hipLaunchKernelGGL(fgh_kernel, dim3(256), dim3(256), 0, stream,
                       x, wq, wk, wv, fbuf, gbuf, hbuf);
    hipLaunchKernelGGL(attn_kernel, dim3(BATCH * 32 * NSPLIT), dim3(256), 0, stream,
                       fbuf, gbuf, hbuf, o_acc, l_acc);
    hipLaunchKernelGGL(final_kernel, dim3((BATCH * CDIM * NSEQ) / 256), dim3(256), 0, stream,
                       x, o_acc, l_acc, gamma, out);
}

// Round 3
// 67.822 us; speedup vs baseline: 4.2059x; 1.4876x over previous
//
#include <hip/hip_runtime.h>
#include <hip/hip_bf16.h>
#include <cmath>

#define BATCH  4
#define CDIM   64
#define CK     8
#define NSEQ   4096
#define NSPLIT 4
#define MT     128                    // m per block: 4 waves x 32
#define NT     128                    // n per staged h tile
#define NCHUNK (NSEQ / NSPLIT)        // 1024 n per block
#define ITERS  (NCHUNK / NT)          // 8
#define HSTR   132                    // s_h row stride in shorts (264B, b64-aligned)

typedef __attribute__((ext_vector_type(8)))  short short8;
typedef __attribute__((ext_vector_type(16))) float f32x16;

__device__ inline unsigned short f2bf(float f) {
    union { float f; unsigned u; } v; v.f = f;
    unsigned r = v.u + 0x7fff + ((v.u >> 16) & 1);   // RNE
    return (unsigned short)(r >> 16);
}
__device__ inline float bf2f(unsigned short h) {
    union { unsigned u; float f; } v; v.u = ((unsigned)h) << 16;
    return v.f;
}

// -------------------------------------------------------------------------
// Kernel 1: f = wq@x, g = wk@x, h = wv@x.
// Outputs: f_pair/g_pair[B][N][16] bf16 {hi x8 | lo x8}; h_bf[B][C][N] bf16.
// -------------------------------------------------------------------------
__global__ __launch_bounds__(256) void fgh_kernel(
    const float* __restrict__ x,  const float* __restrict__ wq,
    const float* __restrict__ wk, const float* __restrict__ wv,
    unsigned short* __restrict__ f_pair, unsigned short* __restrict__ g_pair,
    unsigned short* __restrict__ h_bf)
{
    __shared__ __align__(16) float s_wq[CDIM][CK];
    __shared__ __align__(16) float s_wk[CDIM][CK];
    __shared__ __align__(16) float s_wv[CDIM][68];

    const int t = threadIdx.x;
    #pragma unroll
    for (int u = 0; u < 2; ++u) {
        const int i = t + u * 256;
        const int k = i >> 6, c = i & 63;
        s_wq[c][k] = wq[i];
        s_wk[c][k] = wk[i];
    }
    #pragma unroll
    for (int u = 0; u < 16; ++u) {
        const int i = t + u * 256;
        const int d = i >> 6, c = i & 63;
        s_wv[c][d] = wv[i];
    }
    __syncthreads();

    const int b  = blockIdx.x >> 6;
    const int n0 = (blockIdx.x & 63) * 64;
    const int nl = t >> 2;
    const int q  = t & 3;
    const int n  = n0 + nl;

    float fa[CK]   = {0.f};
    float ga[CK]   = {0.f};
    float ha[CDIM] = {0.f};

    #pragma unroll
    for (int ci = 0; ci < 16; ++ci) {
        const int c   = q * 16 + ci;
        const float xv = x[(b * CDIM + c) * NSEQ + n];

        const float4 q0 = *(const float4*)&s_wq[c][0];
        const float4 q1 = *(const float4*)&s_wq[c][4];
        fa[0] += q0.x * xv; fa[1] += q0.y * xv; fa[2] += q0.z * xv; fa[3] += q0.w * xv;
        fa[4] += q1.x * xv; fa[5] += q1.y * xv; fa[6] += q1.z * xv; fa[7] += q1.w * xv;

        const float4 k0  = *(const float4*)&s_wk[c][0];
        const float4 k1v = *(const float4*)&s_wk[c][4];
        ga[0] += k0.x * xv; ga[1] += k0.y * xv; ga[2] += k0.z * xv; ga[3] += k0.w * xv;
        ga[4] += k1v.x * xv; ga[5] += k1v.y * xv; ga[6] += k1v.z * xv; ga[7] += k1v.w * xv;

        #pragma unroll
        for (int u = 0; u < 16; ++u) {
            const float4 v = *(const float4*)&s_wv[c][u * 4];
            ha[u*4+0] += v.x * xv; ha[u*4+1] += v.y * xv;
            ha[u*4+2] += v.z * xv; ha[u*4+3] += v.w * xv;
        }
    }

    #pragma unroll
    for (int k = 0; k < CK; ++k) {
        fa[k] += __shfl_xor(fa[k], 1); fa[k] += __shfl_xor(fa[k], 2);
        ga[k] += __shfl_xor(ga[k], 1); ga[k] += __shfl_xor(ga[k], 2);
    }
    #pragma unroll
    for (int d = 0; d < CDIM; ++d) {
        ha[d] += __shfl_xor(ha[d], 1); ha[d] += __shfl_xor(ha[d], 2);
    }

    // f_pair / g_pair: hi/lo split-bf16, 32B per n, written by q==0 / q==1
    if (q == 0) {
        unsigned short buf[16];
        #pragma unroll
        for (int k = 0; k < CK; ++k) {
            buf[k]     = f2bf(fa[k]);
            buf[8 + k] = f2bf(fa[k] - bf2f(buf[k]));
        }
        uint4* dst = (uint4*)&f_pair[(size_t)(b * NSEQ + n) * 16];
        dst[0] = ((const uint4*)buf)[0];
        dst[1] = ((const uint4*)buf)[1];
    }
    if (q == 1) {
        unsigned short buf[16];
        #pragma unroll
        for (int k = 0; k < CK; ++k) {
            buf[k]     = f2bf(ga[k]);
            buf[8 + k] = f2bf(ga[k] - bf2f(buf[k]));
        }
        uint4* dst = (uint4*)&g_pair[(size_t)(b * NSEQ + n) * 16];
        dst[0] = ((const uint4*)buf)[0];
        dst[1] = ((const uint4*)buf)[1];
    }
    #pragma unroll
    for (int d = 0; d < CDIM; ++d) {
        if ((d >> 4) == q) h_bf[(size_t)(b * CDIM + d) * NSEQ + n] = f2bf(ha[d]);
    }
}

// -------------------------------------------------------------------------
// Kernel 2: all-MFMA flash attention, no-max softmax, n-split x4, plain-store
// partials. Wave w: m = mt*128 + w*32 + lm, all 64 c (2 accs).
// Scores: S = mfma([f_hi|f_lo], [g_hi,g_hi]) + mfma(..., [g_lo,g_lo]) -> exact
// fp32 scores. P=exp(S) packed bf16 in-register, hh-halves exchanged via
// shfl_xor(32), fed as PV B-frags. h tile staged bf16 in LDS [c][132].
// -------------------------------------------------------------------------
__global__ __launch_bounds__(256) void attn_kernel(
    const unsigned short* __restrict__ f_pair,
    const unsigned short* __restrict__ g_pair,
    const unsigned short* __restrict__ h_bf,
    float* __restrict__ o_part, float* __restrict__ l_part)
{
    __shared__ __align__(16) unsigned short s_h[CDIM * HSTR];

    const int t    = threadIdx.x;
    const int lane = t & 63;
    const int w    = t >> 6;
    const int hh   = lane >> 5;
    const int lm   = lane & 31;

    const int bid = blockIdx.x;          // 512 = s(4) * mt(32) * b(4)
    const int s   = bid & (NSPLIT - 1);
    const int mt  = (bid >> 2) & 31;
    const int b   = bid >> 7;

    const int m = mt * MT + w * 32 + lm;

    union U4 { short8 v; uint4 q4; unsigned u[4]; };

    // g B-frags: gh duplicated in both k-halves (same regs for all lanes of a column)
    U4 Bgh, Bgl;
    {
        const uint4* gp = (const uint4*)&g_pair[(size_t)(b * NSEQ + m) * 16];
        Bgh.q4 = gp[0];
        Bgl.q4 = gp[1];
    }

    f32x16 acc0 = {}, acc1 = {};
    float lsum = 0.f;

    const unsigned short* fp = f_pair + (size_t)b * NSEQ * 16;
    const unsigned short* hb = h_bf  + (size_t)b * CDIM * NSEQ;

    for (int it = 0; it < ITERS; ++it) {
        const int n0 = s * NCHUNK + it * NT;
        __syncthreads();
        // stage h tile: global [c][n] bf16 -> s_h[c][HSTR]
        #pragma unroll
        for (int u = 0; u < 4; ++u) {
            const int chunk = u * 256 + t;          // 1024 = 64c x 16 groups of 8n
            const int c  = chunk >> 4;
            const int ng = chunk & 15;
            const uint4 hv = *(const uint4*)&hb[(size_t)c * NSEQ + n0 + ng * 8];
            *(uint2*)&s_h[c * HSTR + ng * 8]     = make_uint2(hv.x, hv.y);
            *(uint2*)&s_h[c * HSTR + ng * 8 + 4] = make_uint2(hv.z, hv.w);
        }
        __syncthreads();

        #pragma unroll
        for (int sub = 0; sub < 4; ++sub) {
            const int nb = n0 + sub * 32;

            // f A-frag straight from global (coalesced, L2-resident)
            const short8 Af = *(const short8*)&fp[(size_t)(nb + lm) * 16 + hh * 8];

            f32x16 sc = {};
            sc = __builtin_amdgcn_mfma_f32_32x32x16_bf16(Af, Bgh.v, sc, 0, 0, 0);
            sc = __builtin_amdgcn_mfma_f32_32x32x16_bf16(Af, Bgl.v, sc, 0, 0, 0);

            float e[16];
            #pragma unroll
            for (int r = 0; r < 16; ++r) { e[r] = __expf(sc[r]); lsum += e[r]; }

            // pack exp values to bf16 pairs
            unsigned a[8];
            #pragma unroll
            for (int p = 0; p < 8; ++p) {
                __hip_bfloat162 h2 = __float22bfloat162_rn(make_float2(e[2*p], e[2*p+1]));
                a[p] = *(unsigned*)&h2;
            }
            // exchange hh halves: lane sends what its partner needs
            const unsigned r1 = __shfl_xor(hh ? a[0] : a[2], 32);
            const unsigned r2 = __shfl_xor(hh ? a[1] : a[3], 32);
            const unsigned r3 = __shfl_xor(hh ? a[4] : a[6], 32);
            const unsigned r4 = __shfl_xor(hh ? a[5] : a[7], 32);

            U4 P0, P1;
            P0.u[0] = hh ? r1 : a[0];  P0.u[1] = hh ? r2 : a[1];
            P0.u[2] = hh ? a[2] : r1;  P0.u[3] = hh ? a[3] : r2;
            P1.u[0] = hh ? r3 : a[4];  P1.u[1] = hh ? r4 : a[5];
            P1.u[2] = hh ? a[6] : r3;  P1.u[3] = hh ? a[7] : r4;

            // PV: 2 k-subtiles x 2 c-halves
            union U2x { short8 v; uint2 q[2]; } Ah;
            #pragma unroll
            for (int ks = 0; ks < 2; ++ks) {
                const int ko = sub * 32 + ks * 16 + hh * 8;
                const short8 Pv = ks ? P1.v : P0.v;
                Ah.q[0] = *(const uint2*)&s_h[lm * HSTR + ko];
                Ah.q[1] = *(const uint2*)&s_h[lm * HSTR + ko + 4];
                acc0 = __builtin_amdgcn_mfma_f32_32x32x16_bf16(Ah.v, Pv, acc0, 0, 0, 0);
                Ah.q[0] = *(const uint2*)&s_h[(32 + lm) * HSTR + ko];
                Ah.q[1] = *(const uint2*)&s_h[(32 + lm) * HSTR + ko + 4];
                acc1 = __builtin_amdgcn_mfma_f32_32x32x16_bf16(Ah.v, Pv, acc1, 0, 0, 0);
            }
        }
    }

    // merge l across hh pair; plain-store partials (no atomics)
    const float ltot = lsum + __shfl_xor(lsum, 32);
    if (hh == 0) l_part[(s * BATCH + b) * NSEQ + m] = ltot;

    float* ob = o_part + (size_t)(s * BATCH + b) * CDIM * NSEQ;
    #pragma unroll
    for (int r = 0; r < 16; ++r) {
        const int c0 = (r & 3) + 8 * (r >> 2) + 4 * hh;
        ob[(size_t)c0 * NSEQ + m]        = acc0[r];
        ob[(size_t)(32 + c0) * NSEQ + m] = acc1[r];
    }
}

// -------------------------------------------------------------------------
// Kernel 3: out = gamma * (sum_s o_part) / (sum_s l_part) + x
// -------------------------------------------------------------------------
__global__ __launch_bounds__(256) void final_kernel(
    const float* __restrict__ x, const float* __restrict__ o_part,
    const float* __restrict__ l_part, const float* __restrict__ gamma,
    float* __restrict__ out)
{
    const int i = blockIdx.x * 256 + threadIdx.x;      // 1M elements
    const int m = i & (NSEQ - 1);
    const int b = i >> 18;
    float o = 0.f, l = 0.f;
    #pragma unroll
    for (int s = 0; s < NSPLIT; ++s) {
        o += o_part[(size_t)s * (BATCH * CDIM * NSEQ) + i];
        l += l_part[s * (BATCH * NSEQ) + b * NSEQ + m];
    }
    out[i] = gamma[0] * o / l + x[i];
}

extern "C" void kernel_launch(void* const* d_in, const int* in_sizes, int n_in,
                              void* d_out, int out_size, void* d_ws, size_t ws_size,
                              hipStream_t stream) {
    const float* x     = (const float*)d_in[0];
    const float* wq    = (const float*)d_in[1];
    const float* wk    = (const float*)d_in[2];
    const float* wv    = (const float*)d_in[3];
    const float* gamma = (const float*)d_in[4];
    float* out = (float*)d_out;

    char* wsb = (char*)d_ws;
    unsigned short* f_pair = (unsigned short*)wsb;                        // 512 KB
    unsigned short* g_pair = f_pair + (size_t)BATCH * NSEQ * 16;          // 512 KB
    unsigned short* h_bf   = g_pair + (size_t)BATCH * NSEQ * 16;          // 2 MB
    float* o_part = (float*)(wsb + 3u * 1024 * 1024);                     // 16 MB
    float* l_part = o_part + (size_t)NSPLIT * BATCH * CDIM * NSEQ;        // 256 KB

    hipLaunchKernelGGL(fgh_kernel, dim3(256), dim3(256), 0, stream,
                       x, wq, wk, wv, f_pair, g_pair, h_bf);
    hipLaunchKernelGGL(attn_kernel, dim3(BATCH * 32 * NSPLIT), dim3(256), 0, stream,
                       f_pair, g_pair, h_bf, o_part, l_part);
    hipLaunchKernelGGL(final_kernel, dim3((BATCH * CDIM * NSEQ) / 256), dim3(256), 0, stream,
                       x, o_part, l_part, gamma, out);
}

// Round 4
// 58.159 us; speedup vs baseline: 4.9047x; 1.1661x over previous
//
#include <hip/hip_runtime.h>
#include <hip/hip_bf16.h>
#include <cmath>

#define BATCH  4
#define CDIM   64
#define CK     8
#define NSEQ   4096
#define NSPLIT 8
#define MT     128                    // m per block: 4 waves x 32
#define NT     128                    // n per staged h tile
#define NCHUNK (NSEQ / NSPLIT)        // 512 n per block
#define ITERS  (NCHUNK / NT)          // 4
#define HSTR   132                    // s_h row stride in shorts (264B)
#define LOG2E  1.4426950408889634f

typedef __attribute__((ext_vector_type(8)))  short short8;
typedef __attribute__((ext_vector_type(16))) float f32x16;

__device__ inline unsigned short f2bf(float f) {
    union { float f; unsigned u; } v; v.f = f;
    unsigned r = v.u + 0x7fff + ((v.u >> 16) & 1);   // RNE
    return (unsigned short)(r >> 16);
}
__device__ inline float bf2f(unsigned short h) {
    union { unsigned u; float f; } v; v.u = ((unsigned)h) << 16;
    return v.f;
}

// -------------------------------------------------------------------------
// Kernel 1: f = wq@x, g = wk@x (pre-scaled by log2e), h = wv@x.
// f_pair/g_pair[B][N][16] bf16 {hi x8 | lo x8}; h_bf[B][C][N] bf16.
// -------------------------------------------------------------------------
__global__ __launch_bounds__(256) void fgh_kernel(
    const float* __restrict__ x,  const float* __restrict__ wq,
    const float* __restrict__ wk, const float* __restrict__ wv,
    unsigned short* __restrict__ f_pair, unsigned short* __restrict__ g_pair,
    unsigned short* __restrict__ h_bf)
{
    __shared__ __align__(16) float s_wq[CDIM][CK];
    __shared__ __align__(16) float s_wk[CDIM][CK];
    __shared__ __align__(16) float s_wv[CDIM][68];

    const int t = threadIdx.x;
    #pragma unroll
    for (int u = 0; u < 2; ++u) {
        const int i = t + u * 256;
        const int k = i >> 6, c = i & 63;
        s_wq[c][k] = wq[i];
        s_wk[c][k] = wk[i];
    }
    #pragma unroll
    for (int u = 0; u < 16; ++u) {
        const int i = t + u * 256;
        const int d = i >> 6, c = i & 63;
        s_wv[c][d] = wv[i];
    }
    __syncthreads();

    const int b  = blockIdx.x >> 6;
    const int n0 = (blockIdx.x & 63) * 64;
    const int nl = t >> 2;
    const int q  = t & 3;
    const int n  = n0 + nl;

    float fa[CK]   = {0.f};
    float ga[CK]   = {0.f};
    float ha[CDIM] = {0.f};

    #pragma unroll
    for (int ci = 0; ci < 16; ++ci) {
        const int c   = q * 16 + ci;
        const float xv = x[(b * CDIM + c) * NSEQ + n];

        const float4 q0 = *(const float4*)&s_wq[c][0];
        const float4 q1 = *(const float4*)&s_wq[c][4];
        fa[0] += q0.x * xv; fa[1] += q0.y * xv; fa[2] += q0.z * xv; fa[3] += q0.w * xv;
        fa[4] += q1.x * xv; fa[5] += q1.y * xv; fa[6] += q1.z * xv; fa[7] += q1.w * xv;

        const float4 k0  = *(const float4*)&s_wk[c][0];
        const float4 k1v = *(const float4*)&s_wk[c][4];
        ga[0] += k0.x * xv; ga[1] += k0.y * xv; ga[2] += k0.z * xv; ga[3] += k0.w * xv;
        ga[4] += k1v.x * xv; ga[5] += k1v.y * xv; ga[6] += k1v.z * xv; ga[7] += k1v.w * xv;

        #pragma unroll
        for (int u = 0; u < 16; ++u) {
            const float4 v = *(const float4*)&s_wv[c][u * 4];
            ha[u*4+0] += v.x * xv; ha[u*4+1] += v.y * xv;
            ha[u*4+2] += v.z * xv; ha[u*4+3] += v.w * xv;
        }
    }

    #pragma unroll
    for (int k = 0; k < CK; ++k) {
        fa[k] += __shfl_xor(fa[k], 1); fa[k] += __shfl_xor(fa[k], 2);
        ga[k] += __shfl_xor(ga[k], 1); ga[k] += __shfl_xor(ga[k], 2);
    }
    #pragma unroll
    for (int d = 0; d < CDIM; ++d) {
        ha[d] += __shfl_xor(ha[d], 1); ha[d] += __shfl_xor(ha[d], 2);
    }

    if (q == 0) {
        unsigned short buf[16];
        #pragma unroll
        for (int k = 0; k < CK; ++k) {
            buf[k]     = f2bf(fa[k]);
            buf[8 + k] = f2bf(fa[k] - bf2f(buf[k]));
        }
        uint4* dst = (uint4*)&f_pair[(size_t)(b * NSEQ + n) * 16];
        dst[0] = ((const uint4*)buf)[0];
        dst[1] = ((const uint4*)buf)[1];
    }
    if (q == 1) {
        unsigned short buf[16];
        #pragma unroll
        for (int k = 0; k < CK; ++k) {
            const float gs = ga[k] * LOG2E;          // fold log2e into scores
            buf[k]     = f2bf(gs);
            buf[8 + k] = f2bf(gs - bf2f(buf[k]));
        }
        uint4* dst = (uint4*)&g_pair[(size_t)(b * NSEQ + n) * 16];
        dst[0] = ((const uint4*)buf)[0];
        dst[1] = ((const uint4*)buf)[1];
    }
    #pragma unroll
    for (int d = 0; d < CDIM; ++d) {
        if ((d >> 4) == q) h_bf[(size_t)(b * CDIM + d) * NSEQ + n] = f2bf(ha[d]);
    }
}

// -------------------------------------------------------------------------
// Kernel 2: all-MFMA flash attention, no-max softmax (exp2 of pre-scaled
// scores), n-split x8, T14 pipelined h staging (global->reg early, ds_write
// late, double-buffered regs). bf16 partial stores, no atomics.
// -------------------------------------------------------------------------
__global__ __launch_bounds__(256, 4) void attn_kernel(
    const unsigned short* __restrict__ f_pair,
    const unsigned short* __restrict__ g_pair,
    const unsigned short* __restrict__ h_bf,
    unsigned short* __restrict__ o_part, float* __restrict__ l_part)
{
    __shared__ __align__(16) unsigned short s_h[CDIM * HSTR];

    const int t    = threadIdx.x;
    const int lane = t & 63;
    const int w    = t >> 6;
    const int hh   = lane >> 5;
    const int lm   = lane & 31;

    const int bid = blockIdx.x;          // 1024 = s(8) * mt(32) * b(4)
    const int s   = bid & (NSPLIT - 1);
    const int mt  = (bid >> 3) & 31;
    const int b   = bid >> 8;

    const int m = mt * MT + w * 32 + lm;

    union U4 { short8 v; uint4 q4; unsigned u[4]; };

    U4 Bgh, Bgl;
    {
        const uint4* gp = (const uint4*)&g_pair[(size_t)(b * NSEQ + m) * 16];
        Bgh.q4 = gp[0];
        Bgl.q4 = gp[1];
    }

    f32x16 acc0 = {}, acc1 = {};
    float lsum = 0.f;

    const unsigned short* fp = f_pair + (size_t)b * NSEQ * 16;
    const unsigned short* hb = h_bf  + (size_t)b * CDIM * NSEQ;
    const int base = s * NCHUNK;

    const int c_lo  = t >> 4;            // h stage: c = c_lo + 16u, ng = t&15
    const int ng_st = t & 15;

    auto issueH = [&](int n0, uint4 (&hr)[4]) {
        #pragma unroll
        for (int u = 0; u < 4; ++u)
            hr[u] = *(const uint4*)&hb[(size_t)(c_lo + u * 16) * NSEQ + n0 + ng_st * 8];
    };
    auto writeH = [&](const uint4 (&hr)[4]) {
        #pragma unroll
        for (int u = 0; u < 4; ++u) {
            const int c = c_lo + u * 16;
            *(uint2*)&s_h[c * HSTR + ng_st * 8]     = make_uint2(hr[u].x, hr[u].y);
            *(uint2*)&s_h[c * HSTR + ng_st * 8 + 4] = make_uint2(hr[u].z, hr[u].w);
        }
    };
    auto issueAf = [&](int n0, short8 (&af)[4]) {
        #pragma unroll
        for (int sub = 0; sub < 4; ++sub)
            af[sub] = *(const short8*)&fp[(size_t)(n0 + sub * 32 + lm) * 16 + hh * 8];
    };
    auto compute = [&](const short8 (&af)[4]) {
        #pragma unroll
        for (int sub = 0; sub < 4; ++sub) {
            f32x16 sc = {};
            sc = __builtin_amdgcn_mfma_f32_32x32x16_bf16(af[sub], Bgh.v, sc, 0, 0, 0);
            sc = __builtin_amdgcn_mfma_f32_32x32x16_bf16(af[sub], Bgl.v, sc, 0, 0, 0);

            unsigned a[8];
            #pragma unroll
            for (int p = 0; p < 8; ++p) {
                const float e0 = exp2f(sc[2*p]);
                const float e1 = exp2f(sc[2*p+1]);
                lsum += e0 + e1;
                __hip_bfloat162 h2 = __float22bfloat162_rn(make_float2(e0, e1));
                a[p] = *(unsigned*)&h2;
            }
            const unsigned r1 = __shfl_xor(hh ? a[0] : a[2], 32);
            const unsigned r2 = __shfl_xor(hh ? a[1] : a[3], 32);
            const unsigned r3 = __shfl_xor(hh ? a[4] : a[6], 32);
            const unsigned r4 = __shfl_xor(hh ? a[5] : a[7], 32);

            U4 P0, P1;
            P0.u[0] = hh ? r1 : a[0];  P0.u[1] = hh ? r2 : a[1];
            P0.u[2] = hh ? a[2] : r1;  P0.u[3] = hh ? a[3] : r2;
            P1.u[0] = hh ? r3 : a[4];  P1.u[1] = hh ? r4 : a[5];
            P1.u[2] = hh ? a[6] : r3;  P1.u[3] = hh ? a[7] : r4;

            union U2x { short8 v; uint2 q[2]; } Ah;
            #pragma unroll
            for (int ks = 0; ks < 2; ++ks) {
                const int ko = sub * 32 + ks * 16 + hh * 8;
                const short8 Pv = ks ? P1.v : P0.v;
                Ah.q[0] = *(const uint2*)&s_h[lm * HSTR + ko];
                Ah.q[1] = *(const uint2*)&s_h[lm * HSTR + ko + 4];
                acc0 = __builtin_amdgcn_mfma_f32_32x32x16_bf16(Ah.v, Pv, acc0, 0, 0, 0);
                Ah.q[0] = *(const uint2*)&s_h[(32 + lm) * HSTR + ko];
                Ah.q[1] = *(const uint2*)&s_h[(32 + lm) * HSTR + ko + 4];
                acc1 = __builtin_amdgcn_mfma_f32_32x32x16_bf16(Ah.v, Pv, acc1, 0, 0, 0);
            }
        }
    };

    uint4  hrA[4], hrB[4];
    short8 af[4];

    issueH(base, hrA);                       // prologue: tile 0 in flight

    #pragma unroll
    for (int it = 0; it < ITERS; ++it) {
        __syncthreads();                     // previous compute done with s_h
        if (it & 1) writeH(hrB); else writeH(hrA);
        __syncthreads();
        issueAf(base + it * NT, af);         // current-tile A-frags (L2)
        if (it + 1 < ITERS) {                // next-tile h -> regs (T14)
            if (it & 1) issueH(base + (it + 1) * NT, hrA);
            else        issueH(base + (it + 1) * NT, hrB);
        }
        compute(af);
    }

    const float ltot = lsum + __shfl_xor(lsum, 32);
    if (hh == 0) l_part[(s * BATCH + b) * NSEQ + m] = ltot;

    unsigned short* ob = o_part + (size_t)(s * BATCH + b) * CDIM * NSEQ;
    #pragma unroll
    for (int r = 0; r < 16; ++r) {
        const int c0 = (r & 3) + 8 * (r >> 2) + 4 * hh;
        ob[(size_t)c0 * NSEQ + m]        = f2bf(acc0[r]);
        ob[(size_t)(32 + c0) * NSEQ + m] = f2bf(acc1[r]);
    }
}

// -------------------------------------------------------------------------
// Kernel 3: out = gamma * (sum_s o_part) / (sum_s l_part) + x
// -------------------------------------------------------------------------
__global__ __launch_bounds__(256) void final_kernel(
    const float* __restrict__ x, const unsigned short* __restrict__ o_part,
    const float* __restrict__ l_part, const float* __restrict__ gamma,
    float* __restrict__ out)
{
    const int i = blockIdx.x * 256 + threadIdx.x;      // 1M elements
    const int m = i & (NSEQ - 1);
    const int b = i >> 18;
    float o = 0.f, l = 0.f;
    #pragma unroll
    for (int s = 0; s < NSPLIT; ++s) {
        o += bf2f(o_part[(size_t)s * (BATCH * CDIM * NSEQ) + i]);
        l += l_part[s * (BATCH * NSEQ) + b * NSEQ + m];
    }
    out[i] = gamma[0] * o / l + x[i];
}

extern "C" void kernel_launch(void* const* d_in, const int* in_sizes, int n_in,
                              void* d_out, int out_size, void* d_ws, size_t ws_size,
                              hipStream_t stream) {
    const float* x     = (const float*)d_in[0];
    const float* wq    = (const float*)d_in[1];
    const float* wk    = (const float*)d_in[2];
    const float* wv    = (const float*)d_in[3];
    const float* gamma = (const float*)d_in[4];
    float* out = (float*)d_out;

    char* wsb = (char*)d_ws;
    unsigned short* f_pair = (unsigned short*)wsb;                         // 512 KB
    unsigned short* g_pair = f_pair + (size_t)BATCH * NSEQ * 16;           // 512 KB
    unsigned short* h_bf   = g_pair + (size_t)BATCH * NSEQ * 16;           // 2 MB
    unsigned short* o_part = (unsigned short*)(wsb + 3u * 1024 * 1024);    // 16 MB (bf16)
    float* l_part = (float*)(wsb + 19u * 1024 * 1024);                     // 512 KB
    // total ws use: ~19.5 MB (same proven footprint as round 3)

    hipLaunchKernelGGL(fgh_kernel, dim3(256), dim3(256), 0, stream,
                       x, wq, wk, wv, f_pair, g_pair, h_bf);
    hipLaunchKernelGGL(attn_kernel, dim3(BATCH * 32 * NSPLIT), dim3(256), 0, stream,
                       f_pair, g_pair, h_bf, o_part, l_part);
    hipLaunchKernelGGL(final_kernel, dim3((BATCH * CDIM * NSEQ) / 256), dim3(256), 0, stream,
                       x, o_part, l_part, gamma, out);
}

// Round 5
// 50.341 us; speedup vs baseline: 5.6663x; 1.1553x over previous
//
#include <hip/hip_runtime.h>
#include <hip/hip_bf16.h>
#include <cmath>

#define BATCH  4
#define CDIM   64
#define CK     8
#define NSEQ   4096
#define NSPLIT 8
#define MT     128                    // m per block: 4 waves x 32
#define NT     128                    // n per staged h tile
#define NCHUNK (NSEQ / NSPLIT)        // 512 n per block
#define ITERS  (NCHUNK / NT)          // 4
#define HSTR   132                    // s_h row stride in shorts (264B, b64 pairs, 2-way-free)
#define LOG2E  1.4426950408889634f

typedef __attribute__((ext_vector_type(8)))  short short8;
typedef __attribute__((ext_vector_type(16))) float f32x16;

__device__ inline unsigned short f2bf(float f) {
    union { float f; unsigned u; } v; v.f = f;
    unsigned r = v.u + 0x7fff + ((v.u >> 16) & 1);   // RNE
    return (unsigned short)(r >> 16);
}
__device__ inline float bf2f(unsigned short h) {
    union { unsigned u; float f; } v; v.u = ((unsigned)h) << 16;
    return v.f;
}

// -------------------------------------------------------------------------
// Kernel 1: f = wq@x, g = wk@x (pre-scaled by log2e), h = wv@x.
// f_pair/g_pair[B][N][16] bf16 {hi x8 | lo x8}; h_bf[B][C][N] bf16.
// -------------------------------------------------------------------------
__global__ __launch_bounds__(256) void fgh_kernel(
    const float* __restrict__ x,  const float* __restrict__ wq,
    const float* __restrict__ wk, const float* __restrict__ wv,
    unsigned short* __restrict__ f_pair, unsigned short* __restrict__ g_pair,
    unsigned short* __restrict__ h_bf)
{
    __shared__ __align__(16) float s_wq[CDIM][CK];
    __shared__ __align__(16) float s_wk[CDIM][CK];
    __shared__ __align__(16) float s_wv[CDIM][68];

    const int t = threadIdx.x;
    #pragma unroll
    for (int u = 0; u < 2; ++u) {
        const int i = t + u * 256;
        const int k = i >> 6, c = i & 63;
        s_wq[c][k] = wq[i];
        s_wk[c][k] = wk[i];
    }
    #pragma unroll
    for (int u = 0; u < 16; ++u) {
        const int i = t + u * 256;
        const int d = i >> 6, c = i & 63;
        s_wv[c][d] = wv[i];
    }
    __syncthreads();

    const int b  = blockIdx.x >> 6;
    const int n0 = (blockIdx.x & 63) * 64;
    const int nl = t >> 2;
    const int q  = t & 3;
    const int n  = n0 + nl;

    float fa[CK]   = {0.f};
    float ga[CK]   = {0.f};
    float ha[CDIM] = {0.f};

    #pragma unroll
    for (int ci = 0; ci < 16; ++ci) {
        const int c   = q * 16 + ci;
        const float xv = x[(b * CDIM + c) * NSEQ + n];

        const float4 q0 = *(const float4*)&s_wq[c][0];
        const float4 q1 = *(const float4*)&s_wq[c][4];
        fa[0] += q0.x * xv; fa[1] += q0.y * xv; fa[2] += q0.z * xv; fa[3] += q0.w * xv;
        fa[4] += q1.x * xv; fa[5] += q1.y * xv; fa[6] += q1.z * xv; fa[7] += q1.w * xv;

        const float4 k0  = *(const float4*)&s_wk[c][0];
        const float4 k1v = *(const float4*)&s_wk[c][4];
        ga[0] += k0.x * xv; ga[1] += k0.y * xv; ga[2] += k0.z * xv; ga[3] += k0.w * xv;
        ga[4] += k1v.x * xv; ga[5] += k1v.y * xv; ga[6] += k1v.z * xv; ga[7] += k1v.w * xv;

        #pragma unroll
        for (int u = 0; u < 16; ++u) {
            const float4 v = *(const float4*)&s_wv[c][u * 4];
            ha[u*4+0] += v.x * xv; ha[u*4+1] += v.y * xv;
            ha[u*4+2] += v.z * xv; ha[u*4+3] += v.w * xv;
        }
    }

    #pragma unroll
    for (int k = 0; k < CK; ++k) {
        fa[k] += __shfl_xor(fa[k], 1); fa[k] += __shfl_xor(fa[k], 2);
        ga[k] += __shfl_xor(ga[k], 1); ga[k] += __shfl_xor(ga[k], 2);
    }
    #pragma unroll
    for (int d = 0; d < CDIM; ++d) {
        ha[d] += __shfl_xor(ha[d], 1); ha[d] += __shfl_xor(ha[d], 2);
    }

    if (q == 0) {
        unsigned short buf[16];
        #pragma unroll
        for (int k = 0; k < CK; ++k) {
            buf[k]     = f2bf(fa[k]);
            buf[8 + k] = f2bf(fa[k] - bf2f(buf[k]));
        }
        uint4* dst = (uint4*)&f_pair[(size_t)(b * NSEQ + n) * 16];
        dst[0] = ((const uint4*)buf)[0];
        dst[1] = ((const uint4*)buf)[1];
    }
    if (q == 1) {
        unsigned short buf[16];
        #pragma unroll
        for (int k = 0; k < CK; ++k) {
            const float gs = ga[k] * LOG2E;          // fold log2e into scores
            buf[k]     = f2bf(gs);
            buf[8 + k] = f2bf(gs - bf2f(buf[k]));
        }
        uint4* dst = (uint4*)&g_pair[(size_t)(b * NSEQ + n) * 16];
        dst[0] = ((const uint4*)buf)[0];
        dst[1] = ((const uint4*)buf)[1];
    }
    #pragma unroll
    for (int d = 0; d < CDIM; ++d) {
        if ((d >> 4) == q) h_bf[(size_t)(b * CDIM + d) * NSEQ + n] = f2bf(ha[d]);
    }
}

// -------------------------------------------------------------------------
// Kernel 2: all-MFMA flash attention, no-max softmax (raw v_exp_f32 of
// pre-scaled scores), n-split x8, T14 pipelined h staging, T12
// permlane32_swap P-exchange (no ds_bpermute, no cndmask), bf16 partials.
// -------------------------------------------------------------------------
__global__ __launch_bounds__(256, 4) void attn_kernel(
    const unsigned short* __restrict__ f_pair,
    const unsigned short* __restrict__ g_pair,
    const unsigned short* __restrict__ h_bf,
    unsigned short* __restrict__ o_part, float* __restrict__ l_part)
{
    __shared__ __align__(16) unsigned short s_h[CDIM * HSTR];

    const int t    = threadIdx.x;
    const int lane = t & 63;
    const int w    = t >> 6;
    const int hh   = lane >> 5;
    const int lm   = lane & 31;

    const int bid = blockIdx.x;          // 1024 = s(8) * mt(32) * b(4)
    const int s   = bid & (NSPLIT - 1);
    const int mt  = (bid >> 3) & 31;
    const int b   = bid >> 8;

    const int m = mt * MT + w * 32 + lm;

    union U4 { short8 v; uint4 q4; unsigned u[4]; };

    U4 Bgh, Bgl;
    {
        const uint4* gp = (const uint4*)&g_pair[(size_t)(b * NSEQ + m) * 16];
        Bgh.q4 = gp[0];
        Bgl.q4 = gp[1];
    }

    f32x16 acc0 = {}, acc1 = {};
    const f32x16 kZero = {};             // score-MFMA C operand, never written
    float lsA = 0.f, lsB = 0.f;          // two independent l chains

    const unsigned short* fp = f_pair + (size_t)b * NSEQ * 16;
    const unsigned short* hb = h_bf  + (size_t)b * CDIM * NSEQ;
    const int base = s * NCHUNK;

    const int c_lo  = t >> 4;            // h stage: c = c_lo + 16u, ng = t&15
    const int ng_st = t & 15;
    // strength-reduced bases
    const unsigned short* fpl = fp + (size_t)lm * 16 + hh * 8;   // + n*16 per access
    const unsigned short* hbl = hb + (size_t)c_lo * NSEQ + ng_st * 8;
    const int shw  = c_lo * HSTR + ng_st * 8;                     // LDS write base
    const int shrA = lm * HSTR;                                   // LDS read bases
    const int shrB = (32 + lm) * HSTR;

    auto issueH = [&](int n0, uint4 (&hr)[4]) {
        #pragma unroll
        for (int u = 0; u < 4; ++u)
            hr[u] = *(const uint4*)&hbl[(size_t)u * 16 * NSEQ + n0];
    };
    auto writeH = [&](const uint4 (&hr)[4]) {
        #pragma unroll
        for (int u = 0; u < 4; ++u) {
            *(uint2*)&s_h[shw + u * 16 * HSTR]     = make_uint2(hr[u].x, hr[u].y);
            *(uint2*)&s_h[shw + u * 16 * HSTR + 4] = make_uint2(hr[u].z, hr[u].w);
        }
    };
    auto issueAf = [&](int n0, short8 (&af)[4]) {
        const unsigned short* p = fpl + (size_t)n0 * 16;
        #pragma unroll
        for (int sub = 0; sub < 4; ++sub)
            af[sub] = *(const short8*)&p[sub * 32 * 16];
    };
    auto compute = [&](const short8 (&af)[4]) {
        #pragma unroll
        for (int sub = 0; sub < 4; ++sub) {
            f32x16 sc = __builtin_amdgcn_mfma_f32_32x32x16_bf16(af[sub], Bgh.v, kZero, 0, 0, 0);
            sc = __builtin_amdgcn_mfma_f32_32x32x16_bf16(af[sub], Bgl.v, sc, 0, 0, 0);

            unsigned a[8];
            #pragma unroll
            for (int p = 0; p < 8; ++p) {
                const float e0 = __builtin_amdgcn_exp2f(sc[2*p]);
                const float e1 = __builtin_amdgcn_exp2f(sc[2*p+1]);
                lsA += e0; lsB += e1;
                __hip_bfloat162 h2 = __float22bfloat162_rn(make_float2(e0, e1));
                a[p] = *(unsigned*)&h2;
            }
            // T12: one permlane32_swap fills two P words (no waits, no selects)
            const auto s02 = __builtin_amdgcn_permlane32_swap(a[0], a[2], false, false);
            const auto s13 = __builtin_amdgcn_permlane32_swap(a[1], a[3], false, false);
            const auto s46 = __builtin_amdgcn_permlane32_swap(a[4], a[6], false, false);
            const auto s57 = __builtin_amdgcn_permlane32_swap(a[5], a[7], false, false);

            U4 P0, P1;
            P0.u[0] = s02[0]; P0.u[1] = s13[0]; P0.u[2] = s02[1]; P0.u[3] = s13[1];
            P1.u[0] = s46[0]; P1.u[1] = s57[0]; P1.u[2] = s46[1]; P1.u[3] = s57[1];

            union U2x { short8 v; uint2 q[2]; } Ah;
            #pragma unroll
            for (int ks = 0; ks < 2; ++ks) {
                const int ko = sub * 32 + ks * 16 + hh * 8;
                const short8 Pv = ks ? P1.v : P0.v;
                Ah.q[0] = *(const uint2*)&s_h[shrA + ko];
                Ah.q[1] = *(const uint2*)&s_h[shrA + ko + 4];
                acc0 = __builtin_amdgcn_mfma_f32_32x32x16_bf16(Ah.v, Pv, acc0, 0, 0, 0);
                Ah.q[0] = *(const uint2*)&s_h[shrB + ko];
                Ah.q[1] = *(const uint2*)&s_h[shrB + ko + 4];
                acc1 = __builtin_amdgcn_mfma_f32_32x32x16_bf16(Ah.v, Pv, acc1, 0, 0, 0);
            }
        }
    };

    uint4  hrA[4], hrB[4];
    short8 af[4];

    issueH(base, hrA);                       // prologue: tile 0 h + f in flight
    issueAf(base, af);

    #pragma unroll
    for (int it = 0; it < ITERS; ++it) {
        __syncthreads();                     // previous compute done with s_h
        if (it & 1) writeH(hrB); else writeH(hrA);
        __syncthreads();
        if (it + 1 < ITERS) {                // next-tile h -> regs (T14)
            if (it & 1) issueH(base + (it + 1) * NT, hrA);
            else        issueH(base + (it + 1) * NT, hrB);
        }
        compute(af);
        if (it + 1 < ITERS) issueAf(base + (it + 1) * NT, af);
    }

    const float lsum = lsA + lsB;
    const float ltot = lsum + __shfl_xor(lsum, 32);
    if (hh == 0) l_part[(s * BATCH + b) * NSEQ + m] = ltot;

    unsigned short* ob = o_part + (size_t)(s * BATCH + b) * CDIM * NSEQ;
    #pragma unroll
    for (int r = 0; r < 16; ++r) {
        const int c0 = (r & 3) + 8 * (r >> 2) + 4 * hh;
        ob[(size_t)c0 * NSEQ + m]        = f2bf(acc0[r]);
        ob[(size_t)(32 + c0) * NSEQ + m] = f2bf(acc1[r]);
    }
}

// -------------------------------------------------------------------------
// Kernel 3: out = gamma * (sum_s o_part) / (sum_s l_part) + x
// -------------------------------------------------------------------------
__global__ __launch_bounds__(256) void final_kernel(
    const float* __restrict__ x, const unsigned short* __restrict__ o_part,
    const float* __restrict__ l_part, const float* __restrict__ gamma,
    float* __restrict__ out)
{
    const int i = blockIdx.x * 256 + threadIdx.x;      // 1M elements
    const int m = i & (NSEQ - 1);
    const int b = i >> 18;
    float o = 0.f, l = 0.f;
    #pragma unroll
    for (int s = 0; s < NSPLIT; ++s) {
        o += bf2f(o_part[(size_t)s * (BATCH * CDIM * NSEQ) + i]);
        l += l_part[s * (BATCH * NSEQ) + b * NSEQ + m];
    }
    out[i] = gamma[0] * o / l + x[i];
}

extern "C" void kernel_launch(void* const* d_in, const int* in_sizes, int n_in,
                              void* d_out, int out_size, void* d_ws, size_t ws_size,
                              hipStream_t stream) {
    const float* x     = (const float*)d_in[0];
    const float* wq    = (const float*)d_in[1];
    const float* wk    = (const float*)d_in[2];
    const float* wv    = (const float*)d_in[3];
    const float* gamma = (const float*)d_in[4];
    float* out = (float*)d_out;

    char* wsb = (char*)d_ws;
    unsigned short* f_pair = (unsigned short*)wsb;                         // 512 KB
    unsigned short* g_pair = f_pair + (size_t)BATCH * NSEQ * 16;           // 512 KB
    unsigned short* h_bf   = g_pair + (size_t)BATCH * NSEQ * 16;           // 2 MB
    unsigned short* o_part = (unsigned short*)(wsb + 3u * 1024 * 1024);    // 16 MB (bf16)
    float* l_part = (float*)(wsb + 19u * 1024 * 1024);                     // 512 KB

    hipLaunchKernelGGL(fgh_kernel, dim3(256), dim3(256), 0, stream,
                       x, wq, wk, wv, f_pair, g_pair, h_bf);
    hipLaunchKernelGGL(attn_kernel, dim3(BATCH * 32 * NSPLIT), dim3(256), 0, stream,
                       f_pair, g_pair, h_bf, o_part, l_part);
    hipLaunchKernelGGL(final_kernel, dim3((BATCH * CDIM * NSEQ) / 256), dim3(256), 0, stream,
                       x, o_part, l_part, gamma, out);
}